// Round 1
// baseline (952.125 us; speedup 1.0000x reference)
//
#include <hip/hip_runtime.h>
#include <hip/hip_bf16.h>
#include <stdint.h>

#define MM 4096
#define KK 4096
#define NN 11008
#define NP8 1376      // NN/8
#define GRP 128

typedef short v8s __attribute__((ext_vector_type(8)));
typedef float v4f __attribute__((ext_vector_type(4)));

__device__ __forceinline__ void async_cp16(const void* g, void* l) {
  __builtin_amdgcn_global_load_lds(
      (const __attribute__((address_space(1))) unsigned int*)g,
      (__attribute__((address_space(3))) unsigned int*)l, 16, 0, 0);
}

// ---------- x fp32 -> bf16 (one-time) ----------
__global__ void cvt_x_kernel(const float* __restrict__ x,
                             __hip_bfloat16* __restrict__ x16) {
  size_t i = ((size_t)blockIdx.x * 256 + threadIdx.x) * 8;
  const float4* p = (const float4*)(x + i);
  float4 a = p[0], b = p[1];
  union { __hip_bfloat16 h[8]; v8s v; } u;
  u.h[0] = __float2bfloat16(a.x); u.h[1] = __float2bfloat16(a.y);
  u.h[2] = __float2bfloat16(a.z); u.h[3] = __float2bfloat16(a.w);
  u.h[4] = __float2bfloat16(b.x); u.h[5] = __float2bfloat16(b.y);
  u.h[6] = __float2bfloat16(b.z); u.h[7] = __float2bfloat16(b.w);
  *(v8s*)(x16 + i) = u.v;
}

// ---------- dequant slice of W into Wt[n_local][k] bf16 (B^T layout) ----------
// grid: (KK/8, nc/256), block 256. Each thread: one n, 8 consecutive k -> 16B store.
__global__ void dequant_kernel(const int* __restrict__ qw,
                               const int* __restrict__ zeros,
                               const float* __restrict__ scales,
                               __hip_bfloat16* __restrict__ wt,
                               int n_base) {
  int k0 = blockIdx.x * 8;
  int n_local = blockIdx.y * 256 + threadIdx.x;
  int n = n_base + n_local;
  int g = k0 / GRP;                       // 8 | 128, slab within one group
  float s = scales[(size_t)g * NN + n];
  float zc = (float)(128 + zeros[(size_t)g * NN + n]);
  int n8 = n >> 3;
  int shift = (n & 7) * 4;
  union { __hip_bfloat16 h[8]; v8s v; } u;
#pragma unroll
  for (int i = 0; i < 8; ++i) {
    int q = qw[(size_t)(k0 + i) * NP8 + n8];
    unsigned nib = ((unsigned)q >> shift) & 0xFu;
    union { unsigned b; float f; } c;
    c.b = (0x4300u | nib) << 16;          // bf16 bits of (128+nib), exact
    u.h[i] = __float2bfloat16((c.f - zc) * s);   // (nib - z) * s
  }
  *(v8s*)(wt + (size_t)n_local * KK + k0) = u.v;
}

// ---------- main GEMM: 128x128 tile, BK=32, 4 waves, m97 structure ----------
// A: x16 [M,K] bf16 (ABF16=true) or x [M,K] fp32 (convert in staging)
// B: Wt [nc,K] bf16 (pre-transposed, k contiguous)
template <bool ABF16>
__global__ void gemm_wq(const void* __restrict__ Asrc,
                        const __hip_bfloat16* __restrict__ Wt,
                        const float* __restrict__ bias,
                        float* __restrict__ out,
                        int n_base) {
  __shared__ __align__(16) __hip_bfloat16 As[128 * 32];
  __shared__ __align__(16) __hip_bfloat16 Bs[128 * 32];
  const int tid = threadIdx.x;
  const int wave = tid >> 6;
  const int lane = tid & 63;
  const int quad = lane >> 4;
  const int l16 = lane & 15;
  const int wm = (wave >> 1) * 64;
  const int wn = (wave & 1) * 64;
  const int m0 = blockIdx.y * 128;
  const int n0 = blockIdx.x * 128;      // local within slice

  v4f acc[4][4];
#pragma unroll
  for (int a = 0; a < 4; ++a)
#pragma unroll
    for (int b = 0; b < 4; ++b)
#pragma unroll
      for (int r = 0; r < 4; ++r) acc[a][b][r] = 0.f;

  for (int k0 = 0; k0 < KK; k0 += 32) {
    __syncthreads();  // prior frag reads done before LDS overwrite
    // ---- stage A (128 rows x 32 k, bf16, unpadded [row][k]) ----
    if constexpr (ABF16) {
      const __hip_bfloat16* x16 = (const __hip_bfloat16*)Asrc;
#pragma unroll
      for (int p = 0; p < 2; ++p) {
        int c = tid + p * 256;          // 512 chunks of 16B
        int row = c >> 2, part = c & 3;
        async_cp16(x16 + (size_t)(m0 + row) * KK + k0 + part * 8, As + c * 8);
      }
    } else {
      const float* x = (const float*)Asrc;
      int row = tid >> 1, half = tid & 1;   // 16 fp32 per thread
      const float4* src = (const float4*)(x + (size_t)(m0 + row) * KK + k0 + half * 16);
      float4 f0 = src[0], f1 = src[1], f2 = src[2], f3 = src[3];
      union { __hip_bfloat16 hh[16]; v8s v[2]; } u;
      u.hh[0] = __float2bfloat16(f0.x);  u.hh[1] = __float2bfloat16(f0.y);
      u.hh[2] = __float2bfloat16(f0.z);  u.hh[3] = __float2bfloat16(f0.w);
      u.hh[4] = __float2bfloat16(f1.x);  u.hh[5] = __float2bfloat16(f1.y);
      u.hh[6] = __float2bfloat16(f1.z);  u.hh[7] = __float2bfloat16(f1.w);
      u.hh[8] = __float2bfloat16(f2.x);  u.hh[9] = __float2bfloat16(f2.y);
      u.hh[10] = __float2bfloat16(f2.z); u.hh[11] = __float2bfloat16(f2.w);
      u.hh[12] = __float2bfloat16(f3.x); u.hh[13] = __float2bfloat16(f3.y);
      u.hh[14] = __float2bfloat16(f3.z); u.hh[15] = __float2bfloat16(f3.w);
      v8s* dst = (v8s*)(As + row * 32 + half * 16);
      dst[0] = u.v[0];
      dst[1] = u.v[1];
    }
    // ---- stage B (128 n-rows x 32 k, bf16, unpadded [n][k]) ----
#pragma unroll
    for (int p = 0; p < 2; ++p) {
      int c = tid + p * 256;
      int row = c >> 2, part = c & 3;
      async_cp16(Wt + (size_t)(n0 + row) * KK + k0 + part * 8, Bs + c * 8);
    }
    __syncthreads();  // compiler drains vmcnt+lgkmcnt before barrier

    // ---- fragments + 16 MFMA ----
    v8s af[4], bf[4];
#pragma unroll
    for (int i = 0; i < 4; ++i)
      af[i] = *(const v8s*)(As + (wm + i * 16 + l16) * 32 + quad * 8);
#pragma unroll
    for (int i = 0; i < 4; ++i)
      bf[i] = *(const v8s*)(Bs + (wn + i * 16 + l16) * 32 + quad * 8);
#pragma unroll
    for (int mi = 0; mi < 4; ++mi)
#pragma unroll
      for (int ni = 0; ni < 4; ++ni)
        acc[mi][ni] = __builtin_amdgcn_mfma_f32_16x16x32_bf16(
            af[mi], bf[ni], acc[mi][ni], 0, 0, 0);
  }

  // ---- epilogue: C/D layout col=lane&15, row=quad*4+reg ----
#pragma unroll
  for (int ni = 0; ni < 4; ++ni) {
    int col = n_base + n0 + wn + ni * 16 + l16;
    float bv = bias[col];
#pragma unroll
    for (int mi = 0; mi < 4; ++mi) {
      int rowb = m0 + wm + mi * 16 + quad * 4;
#pragma unroll
      for (int r = 0; r < 4; ++r)
        out[(size_t)(rowb + r) * NN + col] = acc[mi][ni][r] + bv;
    }
  }
}

// ---------- correct-but-slow fallback (only if ws is tiny) ----------
__global__ void fallback_kernel(const float* __restrict__ x,
                                const int* __restrict__ qw,
                                const int* __restrict__ zeros,
                                const float* __restrict__ scales,
                                const float* __restrict__ bias,
                                float* __restrict__ out) {
  __shared__ float xs[32][33];
  __shared__ int qs[32][4];
  __shared__ float ss[32];
  __shared__ float zz[32];
  int m0 = blockIdx.y * 32, n0 = blockIdx.x * 32;
  int t = threadIdx.x;
  int m_l = t >> 3, n_j = (t & 7) * 4;
  float acc[4] = {0.f, 0.f, 0.f, 0.f};
  for (int k0 = 0; k0 < KK; k0 += 32) {
    __syncthreads();
    for (int i = t; i < 1024; i += 256)
      xs[i >> 5][i & 31] = x[(size_t)(m0 + (i >> 5)) * KK + k0 + (i & 31)];
    if (t < 128) qs[t >> 2][t & 3] = qw[(size_t)(k0 + (t >> 2)) * NP8 + (n0 >> 3) + (t & 3)];
    int g = k0 / GRP;
    if (t < 32) {
      ss[t] = scales[(size_t)g * NN + n0 + t];
      zz[t] = (float)zeros[(size_t)g * NN + n0 + t];
    }
    __syncthreads();
    for (int kk = 0; kk < 32; ++kk) {
      float xv = xs[m_l][kk];
#pragma unroll
      for (int j = 0; j < 4; ++j) {
        int n_l = n_j + j;
        int q = qs[kk][n_l >> 3];
        float nib = (float)((q >> ((n_l & 7) * 4)) & 0xF);
        acc[j] += xv * (nib - zz[n_l]) * ss[n_l];
      }
    }
  }
#pragma unroll
  for (int j = 0; j < 4; ++j) {
    int n = n0 + n_j + j;
    out[(size_t)(m0 + m_l) * NN + n] = acc[j] + bias[n];
  }
}

extern "C" void kernel_launch(void* const* d_in, const int* in_sizes, int n_in,
                              void* d_out, int out_size, void* d_ws, size_t ws_size,
                              hipStream_t stream) {
  const float* x      = (const float*)d_in[0];
  const int* qw       = (const int*)d_in[1];
  const int* zeros    = (const int*)d_in[2];
  const float* scales = (const float*)d_in[3];
  const float* bias   = (const float*)d_in[4];
  float* out          = (float*)d_out;

  const size_t x16_bytes = (size_t)MM * KK * 2;   // 33.6 MB
  const size_t col_bytes = (size_t)KK * 2;        // 8 KB per dequantized n-column
  char* ws = (char*)d_ws;

  bool use_x16 = ws_size >= x16_bytes + 256 * col_bytes;
  size_t wt_off = use_x16 ? x16_bytes : 0;
  size_t avail = (ws_size > wt_off) ? ws_size - wt_off : 0;
  long long nc_ll = (long long)(avail / col_bytes);
  int Nc = (int)((nc_ll / 256) * 256);
  if (Nc > NN) Nc = NN;

  if (Nc < 256) {  // workspace too small for the fast path
    dim3 dg(NN / 32, MM / 32);
    fallback_kernel<<<dg, 256, 0, stream>>>(x, qw, zeros, scales, bias, out);
    return;
  }

  __hip_bfloat16* x16 = (__hip_bfloat16*)ws;
  __hip_bfloat16* wt = (__hip_bfloat16*)(ws + wt_off);

  if (use_x16)
    cvt_x_kernel<<<MM * KK / 8 / 256, 256, 0, stream>>>(x, x16);

  for (int n_base = 0; n_base < NN; n_base += Nc) {
    int nc = NN - n_base;
    if (nc > Nc) nc = Nc;
    dim3 dq(KK / 8, nc / 256);
    dequant_kernel<<<dq, 256, 0, stream>>>(qw, zeros, scales, wt, n_base);
    dim3 dgm(nc / 128, MM / 128);
    if (use_x16)
      gemm_wq<true><<<dgm, 256, 0, stream>>>((const void*)x16, wt, bias, out, n_base);
    else
      gemm_wq<false><<<dgm, 256, 0, stream>>>((const void*)x, wt, bias, out, n_base);
  }
}

// Round 2
// 691.792 us; speedup vs baseline: 1.3763x; 1.3763x over previous
//
#include <hip/hip_runtime.h>
#include <hip/hip_bf16.h>
#include <stdint.h>

#define MM 4096
#define KK 4096
#define NN 11008
#define NP8 1376      // NN/8
#define GRP 128

typedef short v8s __attribute__((ext_vector_type(8)));
typedef float v4f __attribute__((ext_vector_type(4)));

__device__ __forceinline__ void async_cp16(const void* g, void* l) {
  __builtin_amdgcn_global_load_lds(
      (const __attribute__((address_space(1))) unsigned int*)g,
      (__attribute__((address_space(3))) unsigned int*)l, 16, 0, 0);
}

// ---------- x fp32 -> bf16 (one-time) ----------
__global__ void cvt_x_kernel(const float* __restrict__ x,
                             __hip_bfloat16* __restrict__ x16) {
  size_t i = ((size_t)blockIdx.x * 256 + threadIdx.x) * 8;
  const float4* p = (const float4*)(x + i);
  float4 a = p[0], b = p[1];
  union { __hip_bfloat16 h[8]; v8s v; } u;
  u.h[0] = __float2bfloat16(a.x); u.h[1] = __float2bfloat16(a.y);
  u.h[2] = __float2bfloat16(a.z); u.h[3] = __float2bfloat16(a.w);
  u.h[4] = __float2bfloat16(b.x); u.h[5] = __float2bfloat16(b.y);
  u.h[6] = __float2bfloat16(b.z); u.h[7] = __float2bfloat16(b.w);
  *(v8s*)(x16 + i) = u.v;
}

// ---------- dequant slice of W into Wt[n_local][k] bf16 (B^T layout) ----------
// grid: (KK/64, nc/32), block 256. Thread t: n_sub = t>>3, k_sub = (t&7)*8.
// A wave writes 8 n-rows x 128B contiguous runs -> coalesced stores
// (R0's layout scattered 16B stores at 8KB stride -> 4x write amplification).
__global__ void dequant_kernel(const int* __restrict__ qw,
                               const int* __restrict__ zeros,
                               const float* __restrict__ scales,
                               __hip_bfloat16* __restrict__ wt,
                               int n_base) {
  int k0 = blockIdx.x * 64;
  int t = threadIdx.x;
  int n_local = blockIdx.y * 32 + (t >> 3);
  int n = n_base + n_local;
  int ks = (t & 7) * 8;                  // k offset within the 64-k tile
  int g = k0 >> 7;                       // 64-aligned tile never straddles a group
  float s = scales[(size_t)g * NN + n];
  float zc = (float)(128 + zeros[(size_t)g * NN + n]);
  int n8 = n >> 3;
  int shift = (n & 7) * 4;
  union { __hip_bfloat16 h[8]; v8s v; } u;
#pragma unroll
  for (int i = 0; i < 8; ++i) {
    int q = qw[(size_t)(k0 + ks + i) * NP8 + n8];
    unsigned nib = ((unsigned)q >> shift) & 0xFu;
    union { unsigned b; float f; } c;
    c.b = (0x4300u | nib) << 16;          // bf16 bits of (128+nib), exact
    u.h[i] = __float2bfloat16((c.f - zc) * s);   // (nib - z) * s
  }
  *(v8s*)(wt + (size_t)n_local * KK + k0 + ks) = u.v;
}

// ---------- main GEMM: 128x128 tile, BK=32, 4 waves, m97 structure ----------
// Grid is M-FAST: blockIdx.x = m-tile (32 wide), blockIdx.y = n-tile.
// Co-resident blocks then share a small slab of B-tiles (L2-resident) and
// cycle through A (33.6 MB, L3-resident) instead of streaming 86 MB of B
// per m-row (R0's n-fast order thrashed L3 -> 2.2 GB HBM fetch).
template <bool ABF16>
__global__ void gemm_wq(const void* __restrict__ Asrc,
                        const __hip_bfloat16* __restrict__ Wt,
                        const float* __restrict__ bias,
                        float* __restrict__ out,
                        int n_base) {
  __shared__ __align__(16) __hip_bfloat16 As[128 * 32];
  __shared__ __align__(16) __hip_bfloat16 Bs[128 * 32];
  const int tid = threadIdx.x;
  const int wave = tid >> 6;
  const int lane = tid & 63;
  const int quad = lane >> 4;
  const int l16 = lane & 15;
  const int wm = (wave >> 1) * 64;
  const int wn = (wave & 1) * 64;
  const int m0 = blockIdx.x * 128;      // m-fast
  const int n0 = blockIdx.y * 128;      // local within slice

  v4f acc[4][4];
#pragma unroll
  for (int a = 0; a < 4; ++a)
#pragma unroll
    for (int b = 0; b < 4; ++b)
#pragma unroll
      for (int r = 0; r < 4; ++r) acc[a][b][r] = 0.f;

  for (int k0 = 0; k0 < KK; k0 += 32) {
    __syncthreads();  // prior frag reads done before LDS overwrite
    // ---- stage A (128 rows x 32 k, bf16, unpadded [row][k]) ----
    if constexpr (ABF16) {
      const __hip_bfloat16* x16 = (const __hip_bfloat16*)Asrc;
#pragma unroll
      for (int p = 0; p < 2; ++p) {
        int c = tid + p * 256;          // 512 chunks of 16B
        int row = c >> 2, part = c & 3;
        async_cp16(x16 + (size_t)(m0 + row) * KK + k0 + part * 8, As + c * 8);
      }
    } else {
      const float* x = (const float*)Asrc;
      int row = tid >> 1, half = tid & 1;   // 16 fp32 per thread
      const float4* src = (const float4*)(x + (size_t)(m0 + row) * KK + k0 + half * 16);
      float4 f0 = src[0], f1 = src[1], f2 = src[2], f3 = src[3];
      union { __hip_bfloat16 hh[16]; v8s v[2]; } u;
      u.hh[0] = __float2bfloat16(f0.x);  u.hh[1] = __float2bfloat16(f0.y);
      u.hh[2] = __float2bfloat16(f0.z);  u.hh[3] = __float2bfloat16(f0.w);
      u.hh[4] = __float2bfloat16(f1.x);  u.hh[5] = __float2bfloat16(f1.y);
      u.hh[6] = __float2bfloat16(f1.z);  u.hh[7] = __float2bfloat16(f1.w);
      u.hh[8] = __float2bfloat16(f2.x);  u.hh[9] = __float2bfloat16(f2.y);
      u.hh[10] = __float2bfloat16(f2.z); u.hh[11] = __float2bfloat16(f2.w);
      u.hh[12] = __float2bfloat16(f3.x); u.hh[13] = __float2bfloat16(f3.y);
      u.hh[14] = __float2bfloat16(f3.z); u.hh[15] = __float2bfloat16(f3.w);
      v8s* dst = (v8s*)(As + row * 32 + half * 16);
      dst[0] = u.v[0];
      dst[1] = u.v[1];
    }
    // ---- stage B (128 n-rows x 32 k, bf16, unpadded [n][k]) ----
#pragma unroll
    for (int p = 0; p < 2; ++p) {
      int c = tid + p * 256;
      int row = c >> 2, part = c & 3;
      async_cp16(Wt + (size_t)(n0 + row) * KK + k0 + part * 8, Bs + c * 8);
    }
    __syncthreads();  // compiler drains vmcnt+lgkmcnt before barrier

    // ---- fragments + 16 MFMA ----
    v8s af[4], bf[4];
#pragma unroll
    for (int i = 0; i < 4; ++i)
      af[i] = *(const v8s*)(As + (wm + i * 16 + l16) * 32 + quad * 8);
#pragma unroll
    for (int i = 0; i < 4; ++i)
      bf[i] = *(const v8s*)(Bs + (wn + i * 16 + l16) * 32 + quad * 8);
#pragma unroll
    for (int mi = 0; mi < 4; ++mi)
#pragma unroll
      for (int ni = 0; ni < 4; ++ni)
        acc[mi][ni] = __builtin_amdgcn_mfma_f32_16x16x32_bf16(
            af[mi], bf[ni], acc[mi][ni], 0, 0, 0);
  }

  // ---- epilogue: C/D layout col=lane&15, row=quad*4+reg ----
#pragma unroll
  for (int ni = 0; ni < 4; ++ni) {
    int col = n_base + n0 + wn + ni * 16 + l16;
    float bv = bias[col];
#pragma unroll
    for (int mi = 0; mi < 4; ++mi) {
      int rowb = m0 + wm + mi * 16 + quad * 4;
#pragma unroll
      for (int r = 0; r < 4; ++r)
        out[(size_t)(rowb + r) * NN + col] = acc[mi][ni][r] + bv;
    }
  }
}

// ---------- correct-but-slow fallback (only if ws is tiny) ----------
__global__ void fallback_kernel(const float* __restrict__ x,
                                const int* __restrict__ qw,
                                const int* __restrict__ zeros,
                                const float* __restrict__ scales,
                                const float* __restrict__ bias,
                                float* __restrict__ out) {
  __shared__ float xs[32][33];
  __shared__ int qs[32][4];
  __shared__ float ss[32];
  __shared__ float zz[32];
  int m0 = blockIdx.y * 32, n0 = blockIdx.x * 32;
  int t = threadIdx.x;
  int m_l = t >> 3, n_j = (t & 7) * 4;
  float acc[4] = {0.f, 0.f, 0.f, 0.f};
  for (int k0 = 0; k0 < KK; k0 += 32) {
    __syncthreads();
    for (int i = t; i < 1024; i += 256)
      xs[i >> 5][i & 31] = x[(size_t)(m0 + (i >> 5)) * KK + k0 + (i & 31)];
    if (t < 128) qs[t >> 2][t & 3] = qw[(size_t)(k0 + (t >> 2)) * NP8 + (n0 >> 3) + (t & 3)];
    int g = k0 / GRP;
    if (t < 32) {
      ss[t] = scales[(size_t)g * NN + n0 + t];
      zz[t] = (float)zeros[(size_t)g * NN + n0 + t];
    }
    __syncthreads();
    for (int kk = 0; kk < 32; ++kk) {
      float xv = xs[m_l][kk];
#pragma unroll
      for (int j = 0; j < 4; ++j) {
        int n_l = n_j + j;
        int q = qs[kk][n_l >> 3];
        float nib = (float)((q >> ((n_l & 7) * 4)) & 0xF);
        acc[j] += xv * (nib - zz[n_l]) * ss[n_l];
      }
    }
  }
#pragma unroll
  for (int j = 0; j < 4; ++j) {
    int n = n0 + n_j + j;
    out[(size_t)(m0 + m_l) * NN + n] = acc[j] + bias[n];
  }
}

extern "C" void kernel_launch(void* const* d_in, const int* in_sizes, int n_in,
                              void* d_out, int out_size, void* d_ws, size_t ws_size,
                              hipStream_t stream) {
  const float* x      = (const float*)d_in[0];
  const int* qw       = (const int*)d_in[1];
  const int* zeros    = (const int*)d_in[2];
  const float* scales = (const float*)d_in[3];
  const float* bias   = (const float*)d_in[4];
  float* out          = (float*)d_out;

  const size_t x16_bytes = (size_t)MM * KK * 2;   // 33.6 MB
  const size_t col_bytes = (size_t)KK * 2;        // 8 KB per dequantized n-column
  char* ws = (char*)d_ws;

  bool use_x16 = ws_size >= x16_bytes + 256 * col_bytes;
  size_t wt_off = use_x16 ? x16_bytes : 0;
  size_t avail = (ws_size > wt_off) ? ws_size - wt_off : 0;
  long long nc_ll = (long long)(avail / col_bytes);
  int Nc = (int)((nc_ll / 256) * 256);
  if (Nc > NN) Nc = NN;

  if (Nc < 256) {  // workspace too small for the fast path
    dim3 dg(NN / 32, MM / 32);
    fallback_kernel<<<dg, 256, 0, stream>>>(x, qw, zeros, scales, bias, out);
    return;
  }

  __hip_bfloat16* x16 = (__hip_bfloat16*)ws;
  __hip_bfloat16* wt = (__hip_bfloat16*)(ws + wt_off);

  if (use_x16)
    cvt_x_kernel<<<MM * KK / 8 / 256, 256, 0, stream>>>(x, x16);

  for (int n_base = 0; n_base < NN; n_base += Nc) {
    int nc = NN - n_base;
    if (nc > Nc) nc = Nc;
    dim3 dq(KK / 64, nc / 32);
    dequant_kernel<<<dq, 256, 0, stream>>>(qw, zeros, scales, wt, n_base);
    dim3 dgm(MM / 128, nc / 128);   // m-fast: co-resident blocks share B slab
    if (use_x16)
      gemm_wq<true><<<dgm, 256, 0, stream>>>((const void*)x16, wt, bias, out, n_base);
    else
      gemm_wq<false><<<dgm, 256, 0, stream>>>((const void*)x, wt, bias, out, n_base);
  }
}

// Round 3
// 658.280 us; speedup vs baseline: 1.4464x; 1.0509x over previous
//
#include <hip/hip_runtime.h>
#include <hip/hip_bf16.h>
#include <stdint.h>

#define MM 4096
#define KK 4096
#define NN 11008
#define NP8 1376      // NN/8
#define GRP 128

typedef short v8s __attribute__((ext_vector_type(8)));
typedef float v4f __attribute__((ext_vector_type(4)));

__device__ __forceinline__ void async_cp16(const void* g, void* l) {
  __builtin_amdgcn_global_load_lds(
      (const __attribute__((address_space(1))) unsigned int*)g,
      (__attribute__((address_space(3))) unsigned int*)l, 16, 0, 0);
}

// ---------- x fp32 -> bf16 (one-time) ----------
__global__ void cvt_x_kernel(const float* __restrict__ x,
                             __hip_bfloat16* __restrict__ x16) {
  size_t i = ((size_t)blockIdx.x * 256 + threadIdx.x) * 8;
  const float4* p = (const float4*)(x + i);
  float4 a = p[0], b = p[1];
  union { __hip_bfloat16 h[8]; v8s v; } u;
  u.h[0] = __float2bfloat16(a.x); u.h[1] = __float2bfloat16(a.y);
  u.h[2] = __float2bfloat16(a.z); u.h[3] = __float2bfloat16(a.w);
  u.h[4] = __float2bfloat16(b.x); u.h[5] = __float2bfloat16(b.y);
  u.h[6] = __float2bfloat16(b.z); u.h[7] = __float2bfloat16(b.w);
  *(v8s*)(x16 + i) = u.v;
}

// ---------- dequant slice of W into Wt[n_local][k] bf16 (B^T layout) ----------
// Tile: 128 n x 64 k per block; grid (KK/64, nc/128), block 256.
// Phase 1: stage the 1024 qw words through LDS — each word read ONCE, lanes
//   0..15 read a full 64B line (R1 re-read each word 8x as a 4B-granular
//   gather at 5504B stride -> ~215us).
// Phase 2: extract nibbles (LDS reads broadcast over 8-lane groups; [64][17]
//   padding gives 2-way-max bank aliasing = free), store coalesced 128B runs.
__global__ void dequant_kernel(const int* __restrict__ qw,
                               const int* __restrict__ zeros,
                               const float* __restrict__ scales,
                               __hip_bfloat16* __restrict__ wt,
                               int n_base) {
  __shared__ int qs[64 * 17];            // [k][n8], padded 16->17
  const int k0 = blockIdx.x * 64;
  const int nb = blockIdx.y * 128;       // slice-local n of tile
  const int t = threadIdx.x;
  const int n8_0 = (n_base + nb) >> 3;
#pragma unroll
  for (int it = 0; it < 4; ++it) {
    int idx = it * 256 + t;
    int k = idx >> 4, n8l = idx & 15;
    qs[k * 17 + n8l] = qw[(size_t)(k0 + k) * NP8 + n8_0 + n8l];
  }
  __syncthreads();
  const int g = k0 >> 7;                 // 64-tile never straddles a group
  const int n_sub = t >> 3;              // 0..31
  const int ks = (t & 7) * 8;            // k offset within tile
  const int shift = (n_sub & 7) * 4;
#pragma unroll
  for (int rr = 0; rr < 4; ++rr) {
    int n_local = nb + rr * 32 + n_sub;
    int n = n_base + n_local;
    float s = scales[(size_t)g * NN + n];
    float zc = (float)(128 + zeros[(size_t)g * NN + n]);
    int n8l = (rr * 32 + n_sub) >> 3;
    union { __hip_bfloat16 h[8]; v8s v; } u;
#pragma unroll
    for (int i = 0; i < 8; ++i) {
      int q = qs[(ks + i) * 17 + n8l];
      unsigned nib = ((unsigned)q >> shift) & 0xFu;
      union { unsigned b; float f; } c;
      c.b = (0x4300u | nib) << 16;       // bf16 bits of (128+nib), exact
      u.h[i] = __float2bfloat16((c.f - zc) * s);  // (nib - z) * s
    }
    *(v8s*)(wt + (size_t)n_local * KK + k0 + ks) = u.v;
  }
}

// ---------- main GEMM: 128x128 tile, BK=32, 4 waves, m97 structure ----------
// Grid is M-FAST: blockIdx.x = m-tile (32 wide), blockIdx.y = n-tile.
// Co-resident blocks share a small slab of B-tiles (L2-resident) and cycle
// through A (33.6 MB, L3-resident) — R1 verified: FETCH 2.17GB -> 624MB.
template <bool ABF16>
__global__ void gemm_wq(const void* __restrict__ Asrc,
                        const __hip_bfloat16* __restrict__ Wt,
                        const float* __restrict__ bias,
                        float* __restrict__ out,
                        int n_base) {
  __shared__ __align__(16) __hip_bfloat16 As[128 * 32];
  __shared__ __align__(16) __hip_bfloat16 Bs[128 * 32];
  const int tid = threadIdx.x;
  const int wave = tid >> 6;
  const int lane = tid & 63;
  const int quad = lane >> 4;
  const int l16 = lane & 15;
  const int wm = (wave >> 1) * 64;
  const int wn = (wave & 1) * 64;
  const int m0 = blockIdx.x * 128;      // m-fast
  const int n0 = blockIdx.y * 128;      // local within slice

  v4f acc[4][4];
#pragma unroll
  for (int a = 0; a < 4; ++a)
#pragma unroll
    for (int b = 0; b < 4; ++b)
#pragma unroll
      for (int r = 0; r < 4; ++r) acc[a][b][r] = 0.f;

  for (int k0 = 0; k0 < KK; k0 += 32) {
    __syncthreads();  // prior frag reads done before LDS overwrite
    // ---- stage A (128 rows x 32 k, bf16, unpadded [row][k]) ----
    if constexpr (ABF16) {
      const __hip_bfloat16* x16 = (const __hip_bfloat16*)Asrc;
#pragma unroll
      for (int p = 0; p < 2; ++p) {
        int c = tid + p * 256;          // 512 chunks of 16B
        int row = c >> 2, part = c & 3;
        async_cp16(x16 + (size_t)(m0 + row) * KK + k0 + part * 8, As + c * 8);
      }
    } else {
      const float* x = (const float*)Asrc;
      int row = tid >> 1, half = tid & 1;   // 16 fp32 per thread
      const float4* src = (const float4*)(x + (size_t)(m0 + row) * KK + k0 + half * 16);
      float4 f0 = src[0], f1 = src[1], f2 = src[2], f3 = src[3];
      union { __hip_bfloat16 hh[16]; v8s v[2]; } u;
      u.hh[0] = __float2bfloat16(f0.x);  u.hh[1] = __float2bfloat16(f0.y);
      u.hh[2] = __float2bfloat16(f0.z);  u.hh[3] = __float2bfloat16(f0.w);
      u.hh[4] = __float2bfloat16(f1.x);  u.hh[5] = __float2bfloat16(f1.y);
      u.hh[6] = __float2bfloat16(f1.z);  u.hh[7] = __float2bfloat16(f1.w);
      u.hh[8] = __float2bfloat16(f2.x);  u.hh[9] = __float2bfloat16(f2.y);
      u.hh[10] = __float2bfloat16(f2.z); u.hh[11] = __float2bfloat16(f2.w);
      u.hh[12] = __float2bfloat16(f3.x); u.hh[13] = __float2bfloat16(f3.y);
      u.hh[14] = __float2bfloat16(f3.z); u.hh[15] = __float2bfloat16(f3.w);
      v8s* dst = (v8s*)(As + row * 32 + half * 16);
      dst[0] = u.v[0];
      dst[1] = u.v[1];
    }
    // ---- stage B (128 n-rows x 32 k, bf16, unpadded [n][k]) ----
#pragma unroll
    for (int p = 0; p < 2; ++p) {
      int c = tid + p * 256;
      int row = c >> 2, part = c & 3;
      async_cp16(Wt + (size_t)(n0 + row) * KK + k0 + part * 8, Bs + c * 8);
    }
    __syncthreads();  // compiler drains vmcnt+lgkmcnt before barrier

    // ---- fragments + 16 MFMA ----
    v8s af[4], bf[4];
#pragma unroll
    for (int i = 0; i < 4; ++i)
      af[i] = *(const v8s*)(As + (wm + i * 16 + l16) * 32 + quad * 8);
#pragma unroll
    for (int i = 0; i < 4; ++i)
      bf[i] = *(const v8s*)(Bs + (wn + i * 16 + l16) * 32 + quad * 8);
#pragma unroll
    for (int mi = 0; mi < 4; ++mi)
#pragma unroll
      for (int ni = 0; ni < 4; ++ni)
        acc[mi][ni] = __builtin_amdgcn_mfma_f32_16x16x32_bf16(
            af[mi], bf[ni], acc[mi][ni], 0, 0, 0);
  }

  // ---- epilogue: C/D layout col=lane&15, row=quad*4+reg ----
#pragma unroll
  for (int ni = 0; ni < 4; ++ni) {
    int col = n_base + n0 + wn + ni * 16 + l16;
    float bv = bias[col];
#pragma unroll
    for (int mi = 0; mi < 4; ++mi) {
      int rowb = m0 + wm + mi * 16 + quad * 4;
#pragma unroll
      for (int r = 0; r < 4; ++r)
        out[(size_t)(rowb + r) * NN + col] = acc[mi][ni][r] + bv;
    }
  }
}

// ---------- correct-but-slow fallback (only if ws is tiny) ----------
__global__ void fallback_kernel(const float* __restrict__ x,
                                const int* __restrict__ qw,
                                const int* __restrict__ zeros,
                                const float* __restrict__ scales,
                                const float* __restrict__ bias,
                                float* __restrict__ out) {
  __shared__ float xs[32][33];
  __shared__ int qs[32][4];
  __shared__ float ss[32];
  __shared__ float zz[32];
  int m0 = blockIdx.y * 32, n0 = blockIdx.x * 32;
  int t = threadIdx.x;
  int m_l = t >> 3, n_j = (t & 7) * 4;
  float acc[4] = {0.f, 0.f, 0.f, 0.f};
  for (int k0 = 0; k0 < KK; k0 += 32) {
    __syncthreads();
    for (int i = t; i < 1024; i += 256)
      xs[i >> 5][i & 31] = x[(size_t)(m0 + (i >> 5)) * KK + k0 + (i & 31)];
    if (t < 128) qs[t >> 2][t & 3] = qw[(size_t)(k0 + (t >> 2)) * NP8 + (n0 >> 3) + (t & 3)];
    int g = k0 / GRP;
    if (t < 32) {
      ss[t] = scales[(size_t)g * NN + n0 + t];
      zz[t] = (float)zeros[(size_t)g * NN + n0 + t];
    }
    __syncthreads();
    for (int kk = 0; kk < 32; ++kk) {
      float xv = xs[m_l][kk];
#pragma unroll
      for (int j = 0; j < 4; ++j) {
        int n_l = n_j + j;
        int q = qs[kk][n_l >> 3];
        float nib = (float)((q >> ((n_l & 7) * 4)) & 0xF);
        acc[j] += xv * (nib - zz[n_l]) * ss[n_l];
      }
    }
  }
#pragma unroll
  for (int j = 0; j < 4; ++j) {
    int n = n0 + n_j + j;
    out[(size_t)(m0 + m_l) * NN + n] = acc[j] + bias[n];
  }
}

extern "C" void kernel_launch(void* const* d_in, const int* in_sizes, int n_in,
                              void* d_out, int out_size, void* d_ws, size_t ws_size,
                              hipStream_t stream) {
  const float* x      = (const float*)d_in[0];
  const int* qw       = (const int*)d_in[1];
  const int* zeros    = (const int*)d_in[2];
  const float* scales = (const float*)d_in[3];
  const float* bias   = (const float*)d_in[4];
  float* out          = (float*)d_out;

  const size_t x16_bytes = (size_t)MM * KK * 2;   // 33.6 MB
  const size_t col_bytes = (size_t)KK * 2;        // 8 KB per dequantized n-column
  char* ws = (char*)d_ws;

  bool use_x16 = ws_size >= x16_bytes + 256 * col_bytes;
  size_t wt_off = use_x16 ? x16_bytes : 0;
  size_t avail = (ws_size > wt_off) ? ws_size - wt_off : 0;
  long long nc_ll = (long long)(avail / col_bytes);
  int Nc = (int)((nc_ll / 256) * 256);
  if (Nc > NN) Nc = NN;

  if (Nc < 256) {  // workspace too small for the fast path
    dim3 dg(NN / 32, MM / 32);
    fallback_kernel<<<dg, 256, 0, stream>>>(x, qw, zeros, scales, bias, out);
    return;
  }

  __hip_bfloat16* x16 = (__hip_bfloat16*)ws;
  __hip_bfloat16* wt = (__hip_bfloat16*)(ws + wt_off);

  if (use_x16)
    cvt_x_kernel<<<MM * KK / 8 / 256, 256, 0, stream>>>(x, x16);

  for (int n_base = 0; n_base < NN; n_base += Nc) {
    int nc = NN - n_base;
    if (nc > Nc) nc = Nc;
    dim3 dq(KK / 64, nc / 128);
    dequant_kernel<<<dq, 256, 0, stream>>>(qw, zeros, scales, wt, n_base);
    dim3 dgm(MM / 128, nc / 128);   // m-fast: co-resident blocks share B slab
    if (use_x16)
      gemm_wq<true><<<dgm, 256, 0, stream>>>((const void*)x16, wt, bias, out, n_base);
    else
      gemm_wq<false><<<dgm, 256, 0, stream>>>((const void*)x, wt, bias, out, n_base);
  }
}